// Round 1
// baseline (1258.507 us; speedup 1.0000x reference)
//
#include <hip/hip_runtime.h>
#include <math.h>

// ---------------------------------------------------------------------------
// GCN 3-layer forward on MI355X.
// Pipeline:
//   1. deg histogram over dst (+1 self loop) -> dinv = 1/sqrt(deg)
//   2. CSR build by destination: scan(deg) -> rowptr, atomic-cursor scatter
//   3. layer k: h = a @ Wk (LDS-staged W), then per-node gather-aggregate
//      out[i] = sum_{e: dst=i} h[src_e]*dinv[src]*dinv[i] + h[i]*dinv[i]^2 + b
//   4. final layer: 6-wide aggregate fused with bias + log_softmax
// ---------------------------------------------------------------------------

#define WS_ALIGN(x) (((x) + 255) & ~(size_t)255)

// ---------------- degree histogram ----------------
__global__ void hist_kernel(const int* __restrict__ dst, int* __restrict__ deg, int E) {
    int e = blockIdx.x * blockDim.x + threadIdx.x;
    if (e < E) atomicAdd(&deg[dst[e]], 1);
}

__global__ void dinv_kernel(const int* __restrict__ deg, float* __restrict__ dinv, int n) {
    int i = blockIdx.x * blockDim.x + threadIdx.x;
    if (i < n) dinv[i] = 1.0f / sqrtf((float)(deg[i] + 1));  // +1 self loop; always > 0
}

// ---------------- scan: deg -> rowptr (exclusive) ----------------
// chunk = 1024 elements; numChunks = ceil(n/1024) must be <= 128 (n=100000 -> 98)
__global__ void chunk_sum_kernel(const int* __restrict__ deg, int* __restrict__ chunkSum, int n) {
    __shared__ int sdata[256];
    int b = blockIdx.x, tid = threadIdx.x;
    int base = b * 1024;
    int s = 0;
    for (int i = tid; i < 1024; i += 256) {
        int idx = base + i;
        if (idx < n) s += deg[idx];
    }
    sdata[tid] = s;
    __syncthreads();
    for (int off = 128; off > 0; off >>= 1) {
        if (tid < off) sdata[tid] += sdata[tid + off];
        __syncthreads();
    }
    if (tid == 0) chunkSum[b] = sdata[0];
}

__global__ void scan_chunks_kernel(const int* __restrict__ chunkSum, int* __restrict__ chunkOff,
                                   int numChunks, int* __restrict__ rowptr_last, int E) {
    // single block of 128 threads; numChunks <= 128
    __shared__ int s[128];
    int tid = threadIdx.x;
    int own = (tid < numChunks) ? chunkSum[tid] : 0;
    s[tid] = own;
    __syncthreads();
    for (int off = 1; off < 128; off <<= 1) {
        int v = (tid >= off) ? s[tid - off] : 0;
        __syncthreads();
        s[tid] += v;
        __syncthreads();
    }
    if (tid < numChunks) chunkOff[tid] = s[tid] - own;  // exclusive
    if (tid == 0) *rowptr_last = E;                     // rowptr[n] = E
}

__global__ void chunk_scan_kernel(const int* __restrict__ deg, const int* __restrict__ chunkOff,
                                  int* __restrict__ rowptr, int* __restrict__ cursor, int n) {
    __shared__ int tsum[256];
    int b = blockIdx.x, tid = threadIdx.x;
    int base = b * 1024 + tid * 4;
    int v[4];
    int s = 0;
    #pragma unroll
    for (int k = 0; k < 4; ++k) {
        int idx = base + k;
        v[k] = (idx < n) ? deg[idx] : 0;
        s += v[k];
    }
    int own = s;
    tsum[tid] = s;
    __syncthreads();
    for (int off = 1; off < 256; off <<= 1) {
        int u = (tid >= off) ? tsum[tid - off] : 0;
        __syncthreads();
        tsum[tid] += u;
        __syncthreads();
    }
    int run = tsum[tid] - own + chunkOff[b];  // exclusive prefix for first of my 4
    #pragma unroll
    for (int k = 0; k < 4; ++k) {
        int idx = base + k;
        if (idx < n) {
            rowptr[idx] = run;
            cursor[idx] = run;
            run += v[k];
        }
    }
}

// ---------------- CSR scatter (group edges by dst) ----------------
__global__ void scatter_kernel(const int* __restrict__ src, const int* __restrict__ dst,
                               int* __restrict__ cursor, int* __restrict__ srcSorted, int E) {
    int e = blockIdx.x * blockDim.x + threadIdx.x;
    if (e < E) {
        int d = dst[e];
        int pos = atomicAdd(&cursor[d], 1);
        srcSorted[pos] = src[e];
    }
}

// ---------------- linear: Y[n][64] = X[n][K] @ W[K][64] ----------------
template <int K>
__global__ __launch_bounds__(256) void linear_kernel(const float* __restrict__ X,
                                                     const float* __restrict__ W,
                                                     float* __restrict__ Y, int n) {
    __shared__ float Wl[K * 64];
    __shared__ float Xs[4][K];
    const int tid = threadIdx.x;
    for (int i = tid; i < K * 64; i += 256) Wl[i] = W[i];
    const int feat = tid & 63;
    const int sub = tid >> 6;  // wave id in block; whole wave shares one node
    for (int base = blockIdx.x * 4; base < n; base += gridDim.x * 4) {
        __syncthreads();  // protect Xs (and Wl on first pass)
        for (int i = tid; i < 4 * K; i += 256) {
            int r = i / K, c = i % K;
            int node = base + r;
            Xs[r][c] = (node < n) ? X[(size_t)node * K + c] : 0.f;
        }
        __syncthreads();
        int node = base + sub;
        if (node < n) {
            float acc = 0.f;
            #pragma unroll
            for (int k = 0; k < K; ++k) acc = fmaf(Xs[sub][k], Wl[k * 64 + feat], acc);
            Y[(size_t)node * 64 + feat] = acc;
        }
    }
}

// ---------------- linear3: Y[n][6] = X[n][64] @ W[64][6] ----------------
__global__ __launch_bounds__(256) void linear3_kernel(const float* __restrict__ X,
                                                      const float* __restrict__ W,
                                                      float* __restrict__ Y, int n) {
    __shared__ float Wl[64 * 6];
    __shared__ float Xs[32][65];  // +1 pad: subs stride 65 -> no bank conflict
    const int tid = threadIdx.x;
    for (int i = tid; i < 64 * 6; i += 256) Wl[i] = W[i];
    const int sub = tid >> 3;   // 32 nodes per block
    const int feat = tid & 7;   // 8 slots, 6 active
    for (int base = blockIdx.x * 32; base < n; base += gridDim.x * 32) {
        __syncthreads();
        for (int i = tid; i < 32 * 64; i += 256) {
            int r = i >> 6, c = i & 63;
            int node = base + r;
            Xs[r][c] = (node < n) ? X[(size_t)node * 64 + c] : 0.f;
        }
        __syncthreads();
        int node = base + sub;
        if (node < n && feat < 6) {
            float acc = 0.f;
            #pragma unroll
            for (int k = 0; k < 64; ++k) acc = fmaf(Xs[sub][k], Wl[k * 6 + feat], acc);
            Y[(size_t)node * 6 + feat] = acc;
        }
    }
}

// ---------------- aggregate (64 feats): one wave per node ----------------
__global__ __launch_bounds__(256) void aggregate64_kernel(
    const float* __restrict__ H, const float* __restrict__ dinv,
    const int* __restrict__ rowptr, const int* __restrict__ srcs,
    const float* __restrict__ bias, float* __restrict__ Out, int n, int do_relu) {
    int wave = (blockIdx.x * blockDim.x + threadIdx.x) >> 6;
    int lane = threadIdx.x & 63;
    if (wave >= n) return;
    const int i = wave;
    const float di = dinv[i];
    float acc = H[(size_t)i * 64 + lane] * (di * di);  // self loop
    const int e1 = rowptr[i + 1];
    for (int j = rowptr[i]; j < e1; ++j) {
        int s = srcs[j];                 // broadcast load (same addr all lanes)
        float nrm = dinv[s] * di;
        acc = fmaf(H[(size_t)s * 64 + lane], nrm, acc);  // coalesced 256B
    }
    acc += bias[lane];
    if (do_relu) acc = fmaxf(acc, 0.f);
    Out[(size_t)i * 64 + lane] = acc;
}

// ---------------- aggregate (6 feats) + bias + log_softmax ----------------
__global__ __launch_bounds__(256) void aggregate6_lsm_kernel(
    const float* __restrict__ H, const float* __restrict__ dinv,
    const int* __restrict__ rowptr, const int* __restrict__ srcs,
    const float* __restrict__ bias, float* __restrict__ out, int n) {
    int i = blockIdx.x * blockDim.x + threadIdx.x;
    if (i >= n) return;
    const float di = dinv[i];
    const float sw = di * di;
    float a[6];
    #pragma unroll
    for (int f = 0; f < 6; ++f) a[f] = H[(size_t)i * 6 + f] * sw;
    const int e1 = rowptr[i + 1];
    for (int j = rowptr[i]; j < e1; ++j) {
        int s = srcs[j];
        float nrm = dinv[s] * di;
        #pragma unroll
        for (int f = 0; f < 6; ++f) a[f] = fmaf(H[(size_t)s * 6 + f], nrm, a[f]);
    }
    #pragma unroll
    for (int f = 0; f < 6; ++f) a[f] += bias[f];
    float m = a[0];
    #pragma unroll
    for (int f = 1; f < 6; ++f) m = fmaxf(m, a[f]);
    float sum = 0.f;
    #pragma unroll
    for (int f = 0; f < 6; ++f) sum += expf(a[f] - m);
    float lse = m + logf(sum);
    #pragma unroll
    for (int f = 0; f < 6; ++f) out[(size_t)i * 6 + f] = a[f] - lse;
}

// ---------------------------------------------------------------------------
extern "C" void kernel_launch(void* const* d_in, const int* in_sizes, int n_in,
                              void* d_out, int out_size, void* d_ws, size_t ws_size,
                              hipStream_t stream) {
    const float* x  = (const float*)d_in[0];
    const int*   ei = (const int*)d_in[1];
    const float* W1 = (const float*)d_in[2];
    const float* b1 = (const float*)d_in[3];
    const float* W2 = (const float*)d_in[4];
    const float* b2 = (const float*)d_in[5];
    const float* W3 = (const float*)d_in[6];
    const float* b3 = (const float*)d_in[7];
    float* out = (float*)d_out;

    const int n = in_sizes[0] / 128;       // 100000
    const int E = in_sizes[1] / 2;         // 3200000
    const int* src = ei;
    const int* dst = ei + E;

    // ---- workspace carve ----
    char* ws = (char*)d_ws;
    auto carve = [&](size_t bytes) { char* p = ws; ws += WS_ALIGN(bytes); return p; };
    int*   deg       = (int*)  carve((size_t)n * 4);
    float* dinv      = (float*)carve((size_t)n * 4);
    int*   chunkSum  = (int*)  carve(128 * 4);
    int*   chunkOff  = (int*)  carve(128 * 4);
    int*   rowptr    = (int*)  carve((size_t)(n + 1) * 4);
    int*   cursor    = (int*)  carve((size_t)n * 4);
    int*   srcSorted = (int*)  carve((size_t)E * 4);
    float* bufA      = (float*)carve((size_t)n * 64 * 4);
    float* bufB      = (float*)carve((size_t)n * 64 * 4);
    float* bufC      = (float*)carve((size_t)n * 6 * 4);
    (void)ws_size; (void)n_in; (void)out_size;

    const int numChunks = (n + 1023) / 1024;  // 98 (must be <= 128)

    // ---- graph build (every call: ws is re-poisoned) ----
    hipMemsetAsync(deg, 0, (size_t)n * 4, stream);
    hist_kernel<<<(E + 255) / 256, 256, 0, stream>>>(dst, deg, E);
    dinv_kernel<<<(n + 255) / 256, 256, 0, stream>>>(deg, dinv, n);
    chunk_sum_kernel<<<numChunks, 256, 0, stream>>>(deg, chunkSum, n);
    scan_chunks_kernel<<<1, 128, 0, stream>>>(chunkSum, chunkOff, numChunks, rowptr + n, E);
    chunk_scan_kernel<<<numChunks, 256, 0, stream>>>(deg, chunkOff, rowptr, cursor, n);
    scatter_kernel<<<(E + 255) / 256, 256, 0, stream>>>(src, dst, cursor, srcSorted, E);

    // ---- layer 1: x[n,128]@W1 -> aggregate + relu ----
    linear_kernel<128><<<2048, 256, 0, stream>>>(x, W1, bufA, n);
    aggregate64_kernel<<<(n + 3) / 4, 256, 0, stream>>>(bufA, dinv, rowptr, srcSorted, b1, bufB, n, 1);

    // ---- layer 2: [n,64]@W2 -> aggregate + relu ----
    linear_kernel<64><<<2048, 256, 0, stream>>>(bufB, W2, bufA, n);
    aggregate64_kernel<<<(n + 3) / 4, 256, 0, stream>>>(bufA, dinv, rowptr, srcSorted, b2, bufB, n, 1);

    // ---- layer 3: [n,64]@W3 -> aggregate + bias + log_softmax ----
    linear3_kernel<<<2048, 256, 0, stream>>>(bufB, W3, bufC, n);
    aggregate6_lsm_kernel<<<(n + 255) / 256, 256, 0, stream>>>(bufC, dinv, rowptr, srcSorted, b3, out, n);
}